// Round 1
// baseline (261.982 us; speedup 1.0000x reference)
//
#include <hip/hip_runtime.h>
#include <math.h>

#define GSZ 52
#define NA 3
#define NCLS 80
#define CH 85                    // 5 + NCLS
#define NCA (GSZ*GSZ*NA)         // 8112 cell-anchors per batch
#define MAXGT 64
#define CHUNKS 32                // 32 blocks * 256 = 8192 >= 8112

// softplus(x) = log1p(exp(x)) computed stably, matches jax.nn.softplus
__device__ __forceinline__ float softplusf(float x) {
    return log1pf(expf(-fabsf(x))) + fmaxf(x, 0.0f);
}

__global__ void k_init(int* cnt, int B) {
    int t = threadIdx.x;
    if (t < B) cnt[t] = 0;
}

// Gather GT boxes: cells with conf > 0 (exactly the top_k(conf,64)+valid set,
// since conf in {0,1} and <=40 positives per batch).
__global__ void k_scan(const float* __restrict__ tg, int* cnt,
                       float4* gtbox, int* gtidx) {
    int b = blockIdx.y;
    int n = blockIdx.x * 256 + threadIdx.x;
    if (n >= NCA) return;
    size_t base = ((size_t)b * NCA + n) * CH;
    float conf = tg[base + 4];
    if (conf > 0.0f) {
        int pos = atomicAdd(cnt + b, 1);
        if (pos < MAXGT) {
            gtbox[b * MAXGT + pos] =
                make_float4(tg[base + 0], tg[base + 1], tg[base + 2], tg[base + 3]);
            gtidx[b * MAXGT + pos] = n;
        }
    }
}

// Per cell-anchor: decode box, best IoU vs GT list (LDS), all 5 loss terms.
// Block-reduces 5 partial sums, plain-stores to partial[bid*5..+4].
__global__ void k_main(const float* __restrict__ pr, const float* __restrict__ tg,
                       const float* __restrict__ anchors,
                       const int* __restrict__ cnt,
                       const float4* __restrict__ gtbox,
                       const int* __restrict__ gtidx,
                       float* __restrict__ partial) {
    __shared__ float4 sbox[MAXGT];
    __shared__ int    sidx[MAXGT];
    __shared__ float  swsum[4 * 5];

    int b   = blockIdx.y;
    int tid = threadIdx.x;
    int n   = blockIdx.x * 256 + tid;

    int m = min(cnt[b], MAXGT);
    if (tid < MAXGT && tid < m) {
        sbox[tid] = gtbox[b * MAXGT + tid];
        sidx[tid] = gtidx[b * MAXGT + tid];
    }
    __syncthreads();

    float v_txty = 0.f, v_twth = 0.f, v_noobj = 0.f, v_obj = 0.f, v_cls = 0.f;

    if (n < NCA) {
        int a    = n % NA;
        int cell = n / NA;
        int gi   = cell / GSZ;   // offset.y = first grid index
        int gj   = cell % GSZ;   // offset.x = second grid index
        size_t base = ((size_t)b * NCA + n) * CH;

        float px = pr[base + 0], py = pr[base + 1];
        float pw = pr[base + 2], ph = pr[base + 3];
        float pc = pr[base + 4];
        float aw = anchors[2 * a], ah = anchors[2 * a + 1];

        float sx = 1.0f / (1.0f + expf(-px));
        float sy = 1.0f / (1.0f + expf(-py));
        float ew = expf(pw), eh = expf(ph);

        // decoded pred box (pixel coords)
        float bx = (sx + (float)gj) * 8.0f;
        float by = (sy + (float)gi) * 8.0f;
        float bw = ew * aw, bh = eh * ah;
        float areap = bw * bh;

        float best = 0.0f;
        int kobj = -1;
        for (int k = 0; k < m; k++) {
            float4 g = sbox[k];
            if (sidx[k] == n) kobj = k;
            float ix = fminf(bx + bw * 0.5f, g.x + g.z * 0.5f)
                     - fmaxf(bx - bw * 0.5f, g.x - g.z * 0.5f);
            float iy = fminf(by + bh * 0.5f, g.y + g.w * 0.5f)
                     - fmaxf(by - bh * 0.5f, g.y - g.w * 0.5f);
            ix = fmaxf(ix, 0.0f);
            iy = fmaxf(iy, 0.0f);
            float inter = ix * iy;
            float iou = inter / (areap + g.z * g.w - inter + 1e-9f);
            best = fmaxf(best, iou);
        }

        if (kobj >= 0) {
            // object cell: txty + twth + obj_conf + class losses
            float4 g = sbox[kobj];
            float scale = 2.0f - (g.z / 416.0f) * (g.w / 416.0f);
            float dx = sx - (g.x / 8.0f - (float)gj);
            float dy = sy - (g.y / 8.0f - (float)gi);
            v_txty = (dx * dx + dy * dy) * scale;

            float twr = g.z / aw; if (twr == 0.0f) twr = 1.0f;
            float thr = g.w / ah; if (thr == 0.0f) thr = 1.0f;
            twr = fminf(fmaxf(twr, 1e-9f), 1e9f);
            thr = fminf(fmaxf(thr, 1e-9f), 1e9f);
            float pwr = bw / aw; if (pwr == 0.0f) pwr = 1.0f;
            float phr = bh / ah; if (phr == 0.0f) phr = 1.0f;
            pwr = fminf(fmaxf(pwr, 1e-9f), 1e9f);
            phr = fminf(fmaxf(phr, 1e-9f), 1e9f);
            float dw = logf(pwr) - logf(twr);
            float dh = logf(phr) - logf(thr);
            v_twth = (dw * dw + dh * dh) * scale;

            // conf target is exactly 1.0 at obj cells: bce(x,1)=softplus(x)-x
            v_obj = softplusf(pc) - pc;

            float cls = 0.f;
            for (int c = 0; c < NCLS; c++) {
                float x = pr[base + 5 + c];
                float t = tg[base + 5 + c];
                cls += softplusf(x) - x * t;
            }
            v_cls = cls;
        } else {
            // non-obj: conf target is exactly 0 -> bce(x,0)=softplus(x)
            if (best < 0.6f) v_noobj = softplusf(pc);
        }
    }

    // block reduce 5 floats (4 waves of 64)
    float vals[5] = {v_txty, v_twth, v_noobj, v_obj, v_cls};
    int lane = tid & 63;
    int wave = tid >> 6;
#pragma unroll
    for (int i = 0; i < 5; i++) {
        float v = vals[i];
        for (int off = 32; off > 0; off >>= 1) v += __shfl_down(v, off);
        if (lane == 0) swsum[wave * 5 + i] = v;
    }
    __syncthreads();
    if (tid == 0) {
        int bid = blockIdx.y * gridDim.x + blockIdx.x;
#pragma unroll
        for (int i = 0; i < 5; i++) {
            partial[bid * 5 + i] =
                swsum[i] + swsum[5 + i] + swsum[10 + i] + swsum[15 + i];
        }
    }
}

__global__ void k_final(const float* __restrict__ partial, int nblocks, int B,
                        float* __restrict__ out) {
    __shared__ double sred[4 * 5];
    int tid = threadIdx.x;
    double acc[5] = {0, 0, 0, 0, 0};
    for (int idx = tid; idx < nblocks; idx += 256) {
#pragma unroll
        for (int i = 0; i < 5; i++) acc[i] += (double)partial[idx * 5 + i];
    }
    int lane = tid & 63;
    int wave = tid >> 6;
#pragma unroll
    for (int i = 0; i < 5; i++) {
        double v = acc[i];
        for (int off = 32; off > 0; off >>= 1) v += __shfl_down(v, off);
        if (lane == 0) sred[wave * 5 + i] = v;
    }
    __syncthreads();
    if (tid == 0) {
        double tot = 0.0;
#pragma unroll
        for (int i = 0; i < 5; i++) {
            double r = (sred[i] + sred[5 + i] + sred[10 + i] + sred[15 + i]) / (double)B;
            out[i] = (float)r;
            tot += r;
        }
        out[5] = (float)tot;
    }
}

extern "C" void kernel_launch(void* const* d_in, const int* in_sizes, int n_in,
                              void* d_out, int out_size, void* d_ws, size_t ws_size,
                              hipStream_t stream) {
    const float* preds   = (const float*)d_in[0];
    const float* targets = (const float*)d_in[1];
    const float* anchors = (const float*)d_in[2];
    float* out = (float*)d_out;

    int B = in_sizes[0] / (NCA * CH);   // 32

    // ws layout: cnt[B] | pad to 128 | float4 gtbox[B][64] | int gtidx[B][64] | float partial[B*CHUNKS][5]
    char* ws = (char*)d_ws;
    int*    cnt     = (int*)ws;
    float4* gtbox   = (float4*)(ws + 128);
    int*    gtidx   = (int*)(ws + 128 + (size_t)B * MAXGT * sizeof(float4));
    float*  partial = (float*)(ws + 128 + (size_t)B * MAXGT * sizeof(float4)
                                      + (size_t)B * MAXGT * sizeof(int));
    int nblocks = CHUNKS * B;

    k_init<<<1, 64, 0, stream>>>(cnt, B);
    dim3 grid(CHUNKS, B);
    k_scan<<<grid, 256, 0, stream>>>(targets, cnt, gtbox, gtidx);
    k_main<<<grid, 256, 0, stream>>>(preds, targets, anchors, cnt, gtbox, gtidx, partial);
    k_final<<<1, 256, 0, stream>>>(partial, nblocks, B, out);
}